// Round 9
// baseline (96.619 us; speedup 1.0000x reference)
//
#include <hip/hip_runtime.h>
#include <math.h>

namespace {

constexpr int kB  = 2;
constexpr int kN  = 192;
constexpr int kC  = 32;
constexpr int kH  = 64;
constexpr int kNB = 20;
constexpr int kLayers = 2;
constexpr float kInvSqrtN = 0.07216878364870323f;  // 1/sqrt(192)

typedef __attribute__((ext_vector_type(8))) short bf16x8;
typedef __attribute__((ext_vector_type(4))) float f32x4;

__device__ inline unsigned short bf16r(float x) {   // RNE f32->bf16
    unsigned int u = __float_as_uint(x);
    u = (u + 0x7FFFu + ((u >> 16) & 1u)) >> 16;
    return (unsigned short)u;
}

// ---------------- init: packed W0/W1 frags only (2 blocks) ----------------
// wb0[l][kb=0..3][n=0..63][8]  (k = kb*8+i, zero-padded past kNB) -> 2048 ushort/layer
// wb1[l][kb=0..7][n=0..63][8]                                     -> 4096 ushort/layer
__global__ __launch_bounds__(256) void init_kernel(
    const float* __restrict__ W0,
    const float* __restrict__ W1,
    unsigned short* __restrict__ wb0,
    unsigned short* __restrict__ wb1)
{
    const int tid = threadIdx.x;
    if (blockIdx.x == 0) {
#pragma unroll
        for (int q = 0; q < 2; ++q) {
            const int grp = tid * 2 + q;                 // (l*4+kb)*64 + n
            const int l = grp >> 8, kb = (grp >> 6) & 3, n = grp & 63;
            union { bf16x8 v; unsigned short s[8]; } u;
#pragma unroll
            for (int i = 0; i < 8; ++i) {
                const int k = kb * 8 + i;
                u.s[i] = (k < kNB) ? bf16r(W0[(l * kNB + k) * kH + n]) : (unsigned short)0;
            }
            *reinterpret_cast<bf16x8*>(&wb0[(size_t)grp * 8]) = u.v;
        }
    } else {
#pragma unroll
        for (int q = 0; q < 4; ++q) {
            const int grp = tid * 4 + q;                 // (l*8+kb)*64 + n
            const int l = grp >> 9, kb = (grp >> 6) & 7, n = grp & 63;
            union { bf16x8 v; unsigned short s[8]; } u;
#pragma unroll
            for (int i = 0; i < 8; ++i) {
                const int k = kb * 8 + i;
                u.s[i] = bf16r(W1[(l * kH + k) * kH + n]);
            }
            *reinterpret_cast<bf16x8*>(&wb1[(size_t)grp * 8]) = u.v;
        }
    }
}

// ---------------- fused kernel: block = (z, bcol, half). 6 waves, 1 m-tile each. ----------------
// Phase A: G[h,i] for b=bcol -> LDS frag layout (per-block, 2x redundant across halves).
// Phase B: h2[a, bcol*64+h] for 96 a-rows (16 per wave) -> wave-private LDS.
// Phase C: partial[(z*192+bcol)][a][i] += h2[a][K=64] @ G[64][i]  (disjoint a-ranges).
__global__ __launch_bounds__(384) void fused_kernel(
    const float* __restrict__ feat,   // [B*N, C] layer input
    const float* __restrict__ W2,     // [H, C*C] (layer-offset)
    const float* __restrict__ b0,     // [H]
    const float* __restrict__ b1,     // [H]
    const float* __restrict__ xyz,    // [B,N,3]
    const unsigned short* __restrict__ wb0,   // layer-offset
    const unsigned short* __restrict__ wb1,   // layer-offset
    float* __restrict__ partial)      // [z*kN + bcol][kN][kC]
{
    __shared__ float fsh[kC];
    __shared__ __align__(16) unsigned short Gs[8 * kC * 8];   // [kb8][i32][8]  4KB
    __shared__ __align__(16) unsigned short h1b[6][1024];     // per-wave, 12KB
    __shared__ __align__(16) unsigned short h2s[6][1024];     // per-wave [kb8][a16][8], 12KB

    const int tid  = threadIdx.x;
    const int wave = tid >> 6, lane = tid & 63;
    const int g = lane >> 4, l15 = lane & 15;
    const int blk = blockIdx.x;
    const int z = blk / (kN * 2);
    const int rem = blk - z * (kN * 2);
    const int bcol = rem >> 1, half = rem & 1;

    if (tid < kC) fsh[tid] = feat[(z * kN + bcol) * kC + tid];
    __syncthreads();

    // --- phase A: G row for b=bcol into LDS (2048 outputs over 384 threads) ---
#pragma unroll
    for (int p = 0; p < 6; ++p) {
        const int idx = tid + 384 * p;          // 0..2303
        if (idx < 2048) {
            const int h = idx >> 5, i = idx & 31;
            const float* w = W2 + h * (kC * kC) + i * kC;
            float s = 0.f;
#pragma unroll
            for (int j = 0; j < kC; j += 4) {
                const float4 w4 = *reinterpret_cast<const float4*>(&w[j]);
                s = fmaf(w4.x, fsh[j], s);
                s = fmaf(w4.y, fsh[j + 1], s);
                s = fmaf(w4.z, fsh[j + 2], s);
                s = fmaf(w4.w, fsh[j + 3], s);
            }
            Gs[((h >> 3) * kC + i) * 8 + (h & 7)] = bf16r(s);
        }
    }

    // --- per-lane weight frags (pre-packed, L2 broadcast) ---
    bf16x8 w0g[4], w1g[2][4];
    float b0v[4], b1v[4];
#pragma unroll
    for (int nt = 0; nt < 4; ++nt) {
        const int n = nt * 16 + l15;
        w0g[nt] = *reinterpret_cast<const bf16x8*>(&wb0[((size_t)g * kH + n) * 8]);
        b0v[nt] = b0[n];
        b1v[nt] = b1[n];
    }
#pragma unroll
    for (int ks = 0; ks < 2; ++ks)
#pragma unroll
        for (int nt = 0; nt < 4; ++nt)
            w1g[ks][nt] = *reinterpret_cast<const bf16x8*>(
                &wb1[((size_t)(ks * 4 + g) * kH + nt * 16 + l15) * 8]);

    const float bx = xyz[(z * kN + bcol) * 3 + 0];
    const float by = xyz[(z * kN + bcol) * 3 + 1];
    const float bz = xyz[(z * kN + bcol) * 3 + 2];

    __syncthreads();   // Gs ready for all waves

    unsigned short* h1w = h1b[wave];
    unsigned short* h2w = h2s[wave];
    const int m0 = half * 96 + wave * 16;       // this wave's 16 a-rows

    // --- phase B: h2[16 a][64 h] ---
    // A-frag: rb for edge (arow = m0+l15, bcol), k = 8g+i, in-register
    const int arow = m0 + l15;
    const float dx = xyz[(z * kN + arow) * 3 + 0] - bx;
    const float dy = xyz[(z * kN + arow) * 3 + 1] - by;
    const float dz = xyz[(z * kN + arow) * 3 + 2] - bz;
    const float d  = sqrtf(fmaf(dx, dx, fmaf(dy, dy, fmaf(dz, dz, 1e-12f))));
    const float dn = d * (19.0f / 10.0f);       // y_k = clamp(dn - k, -1, 1)
    union { bf16x8 v; unsigned short s[8]; } aU;
#pragma unroll
    for (int i = 0; i < 8; ++i) {
        const float y = fminf(1.f, fmaxf(-1.f, dn - (float)(8 * g + i)));
        aU.s[i] = bf16r(__cosf(1.57079632679f * y));
    }
    const bf16x8 aR = aU.v;                     // k>=20 hits zero-padded W0 frags

    // GEMM-1: h1[16 a][64 h] = rb[16 a][K=32] @ W0[32][64]
#pragma unroll
    for (int nt = 0; nt < 4; ++nt) {
        f32x4 acc = {b0v[nt], b0v[nt], b0v[nt], b0v[nt]};
        acc = __builtin_amdgcn_mfma_f32_16x16x32_bf16(aR, w0g[nt], acc, 0, 0, 0);
        const int h = nt * 16 + l15;
        const int kb = h >> 3, kk = h & 7;
#pragma unroll
        for (int r = 0; r < 4; ++r)
            h1w[(kb * 16 + 4 * g + r) * 8 + kk] = bf16r(fmaxf(acc[r], 0.f));
    }
    // wave-private h1; same-wave LDS RAW ordered via lgkmcnt

    // GEMM-2: h2[16 a][64] = h1[16 a][K=64] @ W1[64][64]
    f32x4 acc2[4];
#pragma unroll
    for (int nt = 0; nt < 4; ++nt)
        acc2[nt] = (f32x4){b1v[nt], b1v[nt], b1v[nt], b1v[nt]};
#pragma unroll
    for (int ks = 0; ks < 2; ++ks) {
        const bf16x8 aH = *reinterpret_cast<const bf16x8*>(
            &h1w[((ks * 4 + g) * 16 + l15) * 8]);
#pragma unroll
        for (int nt = 0; nt < 4; ++nt)
            acc2[nt] = __builtin_amdgcn_mfma_f32_16x16x32_bf16(aH, w1g[ks][nt], acc2[nt], 0, 0, 0);
    }
#pragma unroll
    for (int nt = 0; nt < 4; ++nt) {
        const int h = nt * 16 + l15;
        const int kb = h >> 3, kk = h & 7;
#pragma unroll
        for (int r = 0; r < 4; ++r)
            h2w[(kb * 16 + 4 * g + r) * 8 + kk] = bf16r(fmaxf(acc2[nt][r], 0.f));
    }

    // --- phase C: partial[a][i] = h2[a][K=64] @ G[64][32] (wave-private h2, synced Gs) ---
    bf16x8 bG[2][2];
#pragma unroll
    for (int ks = 0; ks < 2; ++ks)
#pragma unroll
        for (int nt = 0; nt < 2; ++nt)
            bG[ks][nt] = *reinterpret_cast<const bf16x8*>(
                &Gs[((ks * 4 + g) * kC + nt * 16 + l15) * 8]);

    f32x4 acc0 = {0.f, 0.f, 0.f, 0.f}, acc1 = {0.f, 0.f, 0.f, 0.f};
#pragma unroll
    for (int ks = 0; ks < 2; ++ks) {
        const bf16x8 aF = *reinterpret_cast<const bf16x8*>(
            &h2w[((ks * 4 + g) * 16 + l15) * 8]);
        acc0 = __builtin_amdgcn_mfma_f32_16x16x32_bf16(aF, bG[ks][0], acc0, 0, 0, 0);
        acc1 = __builtin_amdgcn_mfma_f32_16x16x32_bf16(aF, bG[ks][1], acc1, 0, 0, 0);
    }
    float* pp = partial + ((size_t)(z * kN + bcol) * kN + m0) * kC;
#pragma unroll
    for (int r = 0; r < 4; ++r) {
        pp[(4 * g + r) * kC + l15]      = acc0[r];
        pp[(4 * g + r) * kC + 16 + l15] = acc1[r];
    }
}

// ---------------- reduce: block=(z,a). out = (sum_b partial + b2@S) * mask / sqrt(n) ----------------
__global__ __launch_bounds__(256) void reduce_kernel(
    const float* __restrict__ partial,   // [z*kN + b][kN][kC]
    const float* __restrict__ feat,      // [B*N, C] layer input (for S)
    const float* __restrict__ b2,        // [C*C] (layer-offset)
    const float* __restrict__ mask,      // [B, N]
    float* __restrict__ dst)             // [B, N, C]
{
    __shared__ float red[8][kC];
    __shared__ float redS[8][kC];
    __shared__ float Ssh[kC], Vsh[kC];

    const int tid = threadIdx.x;
    const int blk = blockIdx.x;              // z*kN + a
    const int z = blk / kN, a = blk - z * kN;
    const int i = tid & 31, s = tid >> 5;    // 8 slices x 32 i

    // fused: partial-sum over b AND S-sum over b, same loop
    float acc = 0.f, accS = 0.f;
    const float* pb = partial + ((size_t)(z * kN + s * 24) * kN + a) * kC + i;
    const float* fb = feat + (size_t)(z * kN + s * 24) * kC + i;
#pragma unroll 4
    for (int q = 0; q < 24; ++q) {
        acc  += pb[(size_t)q * kN * kC];
        accS += fb[q * kC];
    }
    red[s][i] = acc;
    redS[s][i] = accS;
    __syncthreads();

    if (tid < kC) {
        float v = 0.f, sv = 0.f;
#pragma unroll
        for (int q = 0; q < 8; ++q) { v += red[q][tid]; sv += redS[q][tid]; }
        Vsh[tid] = v;
        Ssh[tid] = sv;
    }
    __syncthreads();

    if (tid < kC) {
        float bt = 0.f;
#pragma unroll
        for (int j = 0; j < kC; ++j) bt = fmaf(b2[tid * kC + j], Ssh[j], bt);
        dst[(size_t)blk * kC + tid] = (Vsh[tid] + bt) * kInvSqrtN * mask[z * kN + a];
    }
}

} // namespace

extern "C" void kernel_launch(void* const* d_in, const int* in_sizes, int n_in,
                              void* d_out, int out_size, void* d_ws, size_t ws_size,
                              hipStream_t stream) {
    const float* features = (const float*)d_in[0];
    const float* xyz      = (const float*)d_in[1];
    const float* mask     = (const float*)d_in[2];
    const float* W0       = (const float*)d_in[3];
    const float* b0       = (const float*)d_in[4];
    const float* W1       = (const float*)d_in[5];
    const float* b1       = (const float*)d_in[6];
    const float* W2       = (const float*)d_in[7];
    const float* b2       = (const float*)d_in[8];
    float* out = (float*)d_out;

    // workspace layout (float offsets):
    //   wb0    :       0 ..    2048   (4096 ushort  = 2 layers x 2048)
    //   wb1    :    2048 ..    6144   (8192 ushort  = 2 layers x 4096)
    //   partial:    6144 .. 2365440   (2*192*192*32 f = 9.4MB)
    //   ftmp   : 2365440 .. 2377728
    float* ws = (float*)d_ws;
    unsigned short* wb0 = (unsigned short*)(ws);
    unsigned short* wb1 = (unsigned short*)(ws + 2048);
    float* partial = ws + 6144;
    float* ftmp    = ws + 2365440;

    init_kernel<<<2, 256, 0, stream>>>(W0, W1, wb0, wb1);

    const float* cur = features;
    for (int l = 0; l < kLayers; ++l) {
        float* dst = (l == kLayers - 1) ? out : ftmp;
        fused_kernel<<<kB * kN * 2, 384, 0, stream>>>(
            cur, W2 + (size_t)l * kH * kC * kC,
            b0 + (size_t)l * kH, b1 + (size_t)l * kH,
            xyz, wb0 + (size_t)l * 2048, wb1 + (size_t)l * 4096,
            partial);
        reduce_kernel<<<kB * kN, 256, 0, stream>>>(
            partial, cur, b2 + (size_t)l * kC * kC, mask, dst);
        cur = dst;
    }
}

// Round 10
// 63.724 us; speedup vs baseline: 1.5162x; 1.5162x over previous
//
#include <hip/hip_runtime.h>
#include <math.h>

namespace {

constexpr int kB  = 2;
constexpr int kN  = 192;
constexpr int kC  = 32;
constexpr int kH  = 64;
constexpr int kNB = 20;
constexpr int kLayers = 2;
constexpr float kInvSqrtN = 0.07216878364870323f;  // 1/sqrt(192)

typedef __attribute__((ext_vector_type(8))) short bf16x8;
typedef __attribute__((ext_vector_type(4))) float f32x4;

__device__ inline unsigned short bf16r(float x) {   // RNE f32->bf16
    unsigned int u = __float_as_uint(x);
    u = (u + 0x7FFFu + ((u >> 16) & 1u)) >> 16;
    return (unsigned short)u;
}
__device__ inline float bf2f(unsigned short v) {
    return __uint_as_float(((unsigned int)v) << 16);
}

// ---------------- init: packed W0/W1 frags only (2 blocks) ----------------
// wb0[l][kb=0..3][n=0..63][8]  (k = kb*8+i, zero-padded past kNB) -> 2048 ushort/layer
// wb1[l][kb=0..7][n=0..63][8]                                     -> 4096 ushort/layer
__global__ __launch_bounds__(256) void init_kernel(
    const float* __restrict__ W0,
    const float* __restrict__ W1,
    unsigned short* __restrict__ wb0,
    unsigned short* __restrict__ wb1)
{
    const int tid = threadIdx.x;
    if (blockIdx.x == 0) {
#pragma unroll
        for (int q = 0; q < 2; ++q) {
            const int grp = tid * 2 + q;                 // (l*4+kb)*64 + n
            const int l = grp >> 8, kb = (grp >> 6) & 3, n = grp & 63;
            union { bf16x8 v; unsigned short s[8]; } u;
#pragma unroll
            for (int i = 0; i < 8; ++i) {
                const int k = kb * 8 + i;
                u.s[i] = (k < kNB) ? bf16r(W0[(l * kNB + k) * kH + n]) : (unsigned short)0;
            }
            *reinterpret_cast<bf16x8*>(&wb0[(size_t)grp * 8]) = u.v;
        }
    } else {
#pragma unroll
        for (int q = 0; q < 4; ++q) {
            const int grp = tid * 4 + q;                 // (l*8+kb)*64 + n
            const int l = grp >> 9, kb = (grp >> 6) & 7, n = grp & 63;
            union { bf16x8 v; unsigned short s[8]; } u;
#pragma unroll
            for (int i = 0; i < 8; ++i) {
                const int k = kb * 8 + i;
                u.s[i] = bf16r(W1[(l * kH + k) * kH + n]);
            }
            *reinterpret_cast<bf16x8*>(&wb1[(size_t)grp * 8]) = u.v;
        }
    }
}

// ---------------- fused kernel: block = (z, bcol). 4 waves x 3 m-tiles. ----------------
// Phase A: G[h,i] for b=bcol -> LDS frag layout (scalar feat row, no pre-barrier).
// Phase B: h2[a, bcol*64+h] for all 192 a -> wave-private LDS.
// Phase C: partial[(z*192+bcol)][a][i] = h2[a][K=64] @ G[64][i], stored bf16.
// Single __syncthreads (Gs), placed after phase B for cross-wave overlap.
__global__ __launch_bounds__(256) void fused_kernel(
    const float* __restrict__ feat,   // [B*N, C] layer input
    const float* __restrict__ W2,     // [H, C*C] (layer-offset)
    const float* __restrict__ b0,     // [H]
    const float* __restrict__ b1,     // [H]
    const float* __restrict__ xyz,    // [B,N,3]
    const unsigned short* __restrict__ wb0,   // layer-offset
    const unsigned short* __restrict__ wb1,   // layer-offset
    unsigned short* __restrict__ partialb)    // [z*kN + bcol][kN][kC] bf16
{
    __shared__ __align__(16) unsigned short Gs[8 * kC * 8];     // [kb8][i32][8]  4KB
    __shared__ __align__(16) unsigned short h2s[4][8 * 48 * 8]; // per-wave, 24KB
    __shared__ __align__(16) unsigned short h1b[4][1024];       // 8KB

    const int tid  = threadIdx.x;
    const int wave = tid >> 6, lane = tid & 63;
    const int g = lane >> 4, l15 = lane & 15;
    const int z = blockIdx.x / kN, bcol = blockIdx.x - z * kN;

    // wave-uniform feature row via scalar loads (no LDS, no barrier)
    const float* frow = feat + (size_t)(z * kN + bcol) * kC;
    float fr[kC];
#pragma unroll
    for (int j = 0; j < kC; ++j) fr[j] = frow[j];

    // --- phase A: G row for b=bcol into LDS ---
#pragma unroll
    for (int p = 0; p < 8; ++p) {
        const int idx = tid + 256 * p;          // 0..2047 = h*32+i
        const int h = idx >> 5, i = idx & 31;
        const float* w = W2 + h * (kC * kC) + i * kC;
        float s = 0.f;
#pragma unroll
        for (int j = 0; j < kC; j += 4) {
            const float4 w4 = *reinterpret_cast<const float4*>(&w[j]);
            s = fmaf(w4.x, fr[j], s);
            s = fmaf(w4.y, fr[j + 1], s);
            s = fmaf(w4.z, fr[j + 2], s);
            s = fmaf(w4.w, fr[j + 3], s);
        }
        Gs[((h >> 3) * kC + i) * 8 + (h & 7)] = bf16r(s);
    }

    // --- per-lane weight frags (pre-packed, L2 broadcast) ---
    bf16x8 w0g[4], w1g[2][4];
    float b0v[4], b1v[4];
#pragma unroll
    for (int nt = 0; nt < 4; ++nt) {
        const int n = nt * 16 + l15;
        w0g[nt] = *reinterpret_cast<const bf16x8*>(&wb0[((size_t)g * kH + n) * 8]);
        b0v[nt] = b0[n];
        b1v[nt] = b1[n];
    }
#pragma unroll
    for (int ks = 0; ks < 2; ++ks)
#pragma unroll
        for (int nt = 0; nt < 4; ++nt)
            w1g[ks][nt] = *reinterpret_cast<const bf16x8*>(
                &wb1[((size_t)(ks * 4 + g) * kH + nt * 16 + l15) * 8]);

    const float bx = xyz[(z * kN + bcol) * 3 + 0];
    const float by = xyz[(z * kN + bcol) * 3 + 1];
    const float bz = xyz[(z * kN + bcol) * 3 + 2];

    unsigned short* h1w = h1b[wave];
    unsigned short* h2w = h2s[wave];

    // --- phase B: h2 for a-rows [wave*48, wave*48+48), wave-private LDS ---
#pragma unroll
    for (int t = 0; t < 3; ++t) {
        const int m0 = (wave * 3 + t) * 16;

        // A-frag: rb for edge (arow = m0+l15, bcol), k = 8g+i, in-register
        const int arow = m0 + l15;
        const float dx = xyz[(z * kN + arow) * 3 + 0] - bx;
        const float dy = xyz[(z * kN + arow) * 3 + 1] - by;
        const float dz = xyz[(z * kN + arow) * 3 + 2] - bz;
        const float d  = sqrtf(fmaf(dx, dx, fmaf(dy, dy, fmaf(dz, dz, 1e-12f))));
        const float dn = d * (19.0f / 10.0f);   // y_k = clamp(dn - k, -1, 1)
        union { bf16x8 v; unsigned short s[8]; } aU;
#pragma unroll
        for (int i = 0; i < 8; ++i) {
            const float y = fminf(1.f, fmaxf(-1.f, dn - (float)(8 * g + i)));
            aU.s[i] = bf16r(__cosf(1.57079632679f * y));
        }
        const bf16x8 aR = aU.v;   // k>=20 entries hit zero-padded W0 frags

        // GEMM-1: h1[16 a][64 h] = rb[16 a][K=32] @ W0[32][64]
#pragma unroll
        for (int nt = 0; nt < 4; ++nt) {
            f32x4 acc = {b0v[nt], b0v[nt], b0v[nt], b0v[nt]};
            acc = __builtin_amdgcn_mfma_f32_16x16x32_bf16(aR, w0g[nt], acc, 0, 0, 0);
            const int h = nt * 16 + l15;
            const int kb = h >> 3, kk = h & 7;
#pragma unroll
            for (int r = 0; r < 4; ++r)
                h1w[(kb * 16 + 4 * g + r) * 8 + kk] = bf16r(fmaxf(acc[r], 0.f));
        }
        // wave-private h1; same-wave LDS RAW ordered via lgkmcnt

        // GEMM-2: h2[16 a][64] = h1[16 a][K=64] @ W1[64][64]
        f32x4 acc2[4];
#pragma unroll
        for (int nt = 0; nt < 4; ++nt)
            acc2[nt] = (f32x4){b1v[nt], b1v[nt], b1v[nt], b1v[nt]};
#pragma unroll
        for (int ks = 0; ks < 2; ++ks) {
            const bf16x8 aH = *reinterpret_cast<const bf16x8*>(
                &h1w[((ks * 4 + g) * 16 + l15) * 8]);
#pragma unroll
            for (int nt = 0; nt < 4; ++nt)
                acc2[nt] = __builtin_amdgcn_mfma_f32_16x16x32_bf16(aH, w1g[ks][nt], acc2[nt], 0, 0, 0);
        }
#pragma unroll
        for (int nt = 0; nt < 4; ++nt) {
            const int h = nt * 16 + l15;
            const int kb = h >> 3, kk = h & 7;
#pragma unroll
            for (int r = 0; r < 4; ++r) {
                const int lt = t * 16 + 4 * g + r;   // local a row (0..47)
                h2w[(kb * 48 + lt) * 8 + kk] = bf16r(fmaxf(acc2[nt][r], 0.f));
            }
        }
    }

    __syncthreads();   // Gs ready for all waves (h2w/h1w are wave-private)

    // --- phase C: partial[a][i] = h2[a][K=64] @ G[64][32], store bf16 ---
    bf16x8 bG[2][2];
#pragma unroll
    for (int ks = 0; ks < 2; ++ks)
#pragma unroll
        for (int nt = 0; nt < 2; ++nt)
            bG[ks][nt] = *reinterpret_cast<const bf16x8*>(
                &Gs[((ks * 4 + g) * kC + nt * 16 + l15) * 8]);

#pragma unroll
    for (int t = 0; t < 3; ++t) {
        const int m0 = wave * 48 + t * 16;
        f32x4 acc0 = {0.f, 0.f, 0.f, 0.f}, acc1 = {0.f, 0.f, 0.f, 0.f};
#pragma unroll
        for (int ks = 0; ks < 2; ++ks) {
            const bf16x8 aF = *reinterpret_cast<const bf16x8*>(
                &h2w[((ks * 4 + g) * 48 + t * 16 + l15) * 8]);
            acc0 = __builtin_amdgcn_mfma_f32_16x16x32_bf16(aF, bG[ks][0], acc0, 0, 0, 0);
            acc1 = __builtin_amdgcn_mfma_f32_16x16x32_bf16(aF, bG[ks][1], acc1, 0, 0, 0);
        }
        unsigned short* pp = partialb + ((size_t)(z * kN + bcol) * kN + m0) * kC;
#pragma unroll
        for (int r = 0; r < 4; ++r) {
            pp[(4 * g + r) * kC + l15]      = bf16r(acc0[r]);
            pp[(4 * g + r) * kC + 16 + l15] = bf16r(acc1[r]);
        }
    }
}

// ---------------- reduce: block=(z,a). out = (sum_b partial + b2@S) * mask / sqrt(n) ----------------
__global__ __launch_bounds__(256) void reduce_kernel(
    const unsigned short* __restrict__ partialb, // [z*kN + b][kN][kC] bf16
    const float* __restrict__ feat,      // [B*N, C] layer input (for S)
    const float* __restrict__ b2,        // [C*C] (layer-offset)
    const float* __restrict__ mask,      // [B, N]
    float* __restrict__ dst)             // [B, N, C]
{
    __shared__ float red[8][kC];
    __shared__ float redS[8][kC];
    __shared__ float Ssh[kC], Vsh[kC];

    const int tid = threadIdx.x;
    const int blk = blockIdx.x;              // z*kN + a
    const int z = blk / kN, a = blk - z * kN;
    const int i = tid & 31, s = tid >> 5;    // 8 slices x 32 i

    // fused: partial-sum over b AND S-sum over b, same loop
    float acc = 0.f, accS = 0.f;
    const unsigned short* pb =
        partialb + ((size_t)(z * kN + s * 24) * kN + a) * kC + i;
    const float* fb = feat + (size_t)(z * kN + s * 24) * kC + i;
#pragma unroll 4
    for (int q = 0; q < 24; ++q) {
        acc  += bf2f(pb[(size_t)q * kN * kC]);
        accS += fb[q * kC];
    }
    red[s][i] = acc;
    redS[s][i] = accS;
    __syncthreads();

    if (tid < kC) {
        float v = 0.f, sv = 0.f;
#pragma unroll
        for (int q = 0; q < 8; ++q) { v += red[q][tid]; sv += redS[q][tid]; }
        Vsh[tid] = v;
        Ssh[tid] = sv;
    }
    __syncthreads();

    if (tid < kC) {
        float bt = 0.f;
#pragma unroll
        for (int j = 0; j < kC; ++j) bt = fmaf(b2[tid * kC + j], Ssh[j], bt);
        dst[(size_t)blk * kC + tid] = (Vsh[tid] + bt) * kInvSqrtN * mask[z * kN + a];
    }
}

} // namespace

extern "C" void kernel_launch(void* const* d_in, const int* in_sizes, int n_in,
                              void* d_out, int out_size, void* d_ws, size_t ws_size,
                              hipStream_t stream) {
    const float* features = (const float*)d_in[0];
    const float* xyz      = (const float*)d_in[1];
    const float* mask     = (const float*)d_in[2];
    const float* W0       = (const float*)d_in[3];
    const float* b0       = (const float*)d_in[4];
    const float* W1       = (const float*)d_in[5];
    const float* b1       = (const float*)d_in[6];
    const float* W2       = (const float*)d_in[7];
    const float* b2       = (const float*)d_in[8];
    float* out = (float*)d_out;

    // workspace layout (float offsets):
    //   wb0     :       0 ..    2048   (4096 ushort  = 2 layers x 2048)
    //   wb1     :    2048 ..    6144   (8192 ushort  = 2 layers x 4096)
    //   partialb:    6144 .. 2365440   (2*192*192*32 ushort = 4.7MB)
    //   ftmp    : 2365440 .. 2377728
    float* ws = (float*)d_ws;
    unsigned short* wb0 = (unsigned short*)(ws);
    unsigned short* wb1 = (unsigned short*)(ws + 2048);
    unsigned short* partialb = (unsigned short*)(ws + 6144);
    float* ftmp = ws + 2365440;

    init_kernel<<<2, 256, 0, stream>>>(W0, W1, wb0, wb1);

    const float* cur = features;
    for (int l = 0; l < kLayers; ++l) {
        float* dst = (l == kLayers - 1) ? out : ftmp;
        fused_kernel<<<kB * kN, 256, 0, stream>>>(
            cur, W2 + (size_t)l * kH * kC * kC,
            b0 + (size_t)l * kH, b1 + (size_t)l * kH,
            xyz, wb0 + (size_t)l * 2048, wb1 + (size_t)l * 4096,
            partialb);
        reduce_kernel<<<kB * kN, 256, 0, stream>>>(
            partialb, cur, b2 + (size_t)l * kC * kC, mask, dst);
        cur = dst;
    }
}

// Round 11
// 62.508 us; speedup vs baseline: 1.5457x; 1.0194x over previous
//
#include <hip/hip_runtime.h>
#include <math.h>

namespace {

constexpr int kB  = 2;
constexpr int kN  = 192;
constexpr int kC  = 32;
constexpr int kH  = 64;
constexpr int kNB = 20;
constexpr int kLayers = 2;
constexpr float kInvSqrtN = 0.07216878364870323f;  // 1/sqrt(192)

typedef __attribute__((ext_vector_type(8))) short bf16x8;
typedef __attribute__((ext_vector_type(4))) float f32x4;

__device__ inline unsigned short bf16r(float x) {   // RNE f32->bf16
    unsigned int u = __float_as_uint(x);
    u = (u + 0x7FFFu + ((u >> 16) & 1u)) >> 16;
    return (unsigned short)u;
}
__device__ inline float bf2f(unsigned short v) {
    return __uint_as_float(((unsigned int)v) << 16);
}

// ---------------- init: packed W0/W1 frags only (2 blocks) ----------------
// wb0[l][kb=0..3][n=0..63][8]  (k = kb*8+i, zero-padded past kNB) -> 2048 ushort/layer
// wb1[l][kb=0..7][n=0..63][8]                                     -> 4096 ushort/layer
__global__ __launch_bounds__(256) void init_kernel(
    const float* __restrict__ W0,
    const float* __restrict__ W1,
    unsigned short* __restrict__ wb0,
    unsigned short* __restrict__ wb1)
{
    const int tid = threadIdx.x;
    if (blockIdx.x == 0) {
#pragma unroll
        for (int q = 0; q < 2; ++q) {
            const int grp = tid * 2 + q;                 // (l*4+kb)*64 + n
            const int l = grp >> 8, kb = (grp >> 6) & 3, n = grp & 63;
            union { bf16x8 v; unsigned short s[8]; } u;
#pragma unroll
            for (int i = 0; i < 8; ++i) {
                const int k = kb * 8 + i;
                u.s[i] = (k < kNB) ? bf16r(W0[(l * kNB + k) * kH + n]) : (unsigned short)0;
            }
            *reinterpret_cast<bf16x8*>(&wb0[(size_t)grp * 8]) = u.v;
        }
    } else {
#pragma unroll
        for (int q = 0; q < 4; ++q) {
            const int grp = tid * 4 + q;                 // (l*8+kb)*64 + n
            const int l = grp >> 9, kb = (grp >> 6) & 7, n = grp & 63;
            union { bf16x8 v; unsigned short s[8]; } u;
#pragma unroll
            for (int i = 0; i < 8; ++i) {
                const int k = kb * 8 + i;
                u.s[i] = bf16r(W1[(l * kH + k) * kH + n]);
            }
            *reinterpret_cast<bf16x8*>(&wb1[(size_t)grp * 8]) = u.v;
        }
    }
}

// ---------------- fused kernel: block = (z, bcol). 4 waves x 3 pipelined m-tiles. ----------------
// Phase A: G[h,i] for b=bcol -> LDS frag layout; single barrier right after.
// Per-tile loop (fully unrolled, per-tile LDS slices -> independent chains):
//   rb -> GEMM1 -> h1[t] -> GEMM2 -> h2[t] -> GEMM3 -> store partial rows (bf16).
__global__ __launch_bounds__(256) void fused_kernel(
    const float* __restrict__ feat,   // [B*N, C] layer input
    const float* __restrict__ W2,     // [H, C*C] (layer-offset)
    const float* __restrict__ b0,     // [H]
    const float* __restrict__ b1,     // [H]
    const float* __restrict__ xyz,    // [B,N,3]
    const unsigned short* __restrict__ wb0,   // layer-offset
    const unsigned short* __restrict__ wb1,   // layer-offset
    unsigned short* __restrict__ partialb)    // [z*kN + bcol][kN][kC] bf16
{
    __shared__ __align__(16) unsigned short Gs[8 * kC * 8];   // [kb8][i32][8]  4KB
    __shared__ __align__(16) unsigned short h1b[4][3][1024];  // per-wave, per-tile 24KB
    __shared__ __align__(16) unsigned short h2b[4][3][1024];  // per-wave, per-tile 24KB

    const int tid  = threadIdx.x;
    const int wave = tid >> 6, lane = tid & 63;
    const int g = lane >> 4, l15 = lane & 15;
    const int z = blockIdx.x / kN, bcol = blockIdx.x - z * kN;

    // wave-uniform feature row via scalar loads (no LDS, no barrier)
    const float* frow = feat + (size_t)(z * kN + bcol) * kC;
    float fr[kC];
#pragma unroll
    for (int j = 0; j < kC; ++j) fr[j] = frow[j];

    // --- phase A: G row for b=bcol into LDS ---
#pragma unroll
    for (int p = 0; p < 8; ++p) {
        const int idx = tid + 256 * p;          // 0..2047 = h*32+i
        const int h = idx >> 5, i = idx & 31;
        const float* w = W2 + h * (kC * kC) + i * kC;
        float s = 0.f;
#pragma unroll
        for (int j = 0; j < kC; j += 4) {
            const float4 w4 = *reinterpret_cast<const float4*>(&w[j]);
            s = fmaf(w4.x, fr[j], s);
            s = fmaf(w4.y, fr[j + 1], s);
            s = fmaf(w4.z, fr[j + 2], s);
            s = fmaf(w4.w, fr[j + 3], s);
        }
        Gs[((h >> 3) * kC + i) * 8 + (h & 7)] = bf16r(s);
    }

    // --- per-lane weight frags (pre-packed, L2 broadcast) ---
    bf16x8 w0g[4], w1g[2][4];
    float b0v[4], b1v[4];
#pragma unroll
    for (int nt = 0; nt < 4; ++nt) {
        const int n = nt * 16 + l15;
        w0g[nt] = *reinterpret_cast<const bf16x8*>(&wb0[((size_t)g * kH + n) * 8]);
        b0v[nt] = b0[n];
        b1v[nt] = b1[n];
    }
#pragma unroll
    for (int ks = 0; ks < 2; ++ks)
#pragma unroll
        for (int nt = 0; nt < 4; ++nt)
            w1g[ks][nt] = *reinterpret_cast<const bf16x8*>(
                &wb1[((size_t)(ks * 4 + g) * kH + nt * 16 + l15) * 8]);

    const float bx = xyz[(z * kN + bcol) * 3 + 0];
    const float by = xyz[(z * kN + bcol) * 3 + 1];
    const float bz = xyz[(z * kN + bcol) * 3 + 2];

    __syncthreads();   // Gs ready (only cross-wave dependency)

    // B-frags (G) in registers
    bf16x8 bG[2][2];
#pragma unroll
    for (int ks = 0; ks < 2; ++ks)
#pragma unroll
        for (int nt = 0; nt < 2; ++nt)
            bG[ks][nt] = *reinterpret_cast<const bf16x8*>(
                &Gs[((ks * 4 + g) * kC + nt * 16 + l15) * 8]);

    // --- pipelined per-tile loop: independent LDS slices per t ---
#pragma unroll
    for (int t = 0; t < 3; ++t) {
        const int m0 = (wave * 3 + t) * 16;
        unsigned short* h1w = h1b[wave][t];
        unsigned short* h2w = h2b[wave][t];

        // A-frag: rb for edge (arow = m0+l15, bcol), k = 8g+i, in-register
        const int arow = m0 + l15;
        const float dx = xyz[(z * kN + arow) * 3 + 0] - bx;
        const float dy = xyz[(z * kN + arow) * 3 + 1] - by;
        const float dz = xyz[(z * kN + arow) * 3 + 2] - bz;
        const float d  = sqrtf(fmaf(dx, dx, fmaf(dy, dy, fmaf(dz, dz, 1e-12f))));
        const float dn = d * (19.0f / 10.0f);   // y_k = clamp(dn - k, -1, 1)
        union { bf16x8 v; unsigned short s[8]; } aU;
#pragma unroll
        for (int i = 0; i < 8; ++i) {
            const float y = fminf(1.f, fmaxf(-1.f, dn - (float)(8 * g + i)));
            aU.s[i] = bf16r(__cosf(1.57079632679f * y));
        }
        const bf16x8 aR = aU.v;   // k>=20 entries hit zero-padded W0 frags

        // GEMM-1: h1[16 a][64 h] = rb[16 a][K=32] @ W0[32][64]
#pragma unroll
        for (int nt = 0; nt < 4; ++nt) {
            f32x4 acc = {b0v[nt], b0v[nt], b0v[nt], b0v[nt]};
            acc = __builtin_amdgcn_mfma_f32_16x16x32_bf16(aR, w0g[nt], acc, 0, 0, 0);
            const int h = nt * 16 + l15;
            const int kb = h >> 3, kk = h & 7;
#pragma unroll
            for (int r = 0; r < 4; ++r)
                h1w[(kb * 16 + 4 * g + r) * 8 + kk] = bf16r(fmaxf(acc[r], 0.f));
        }
        // wave-private h1 slice; same-wave LDS RAW ordered via lgkmcnt

        // GEMM-2: h2[16 a][64] = h1[16 a][K=64] @ W1[64][64]
        f32x4 acc2[4];
#pragma unroll
        for (int nt = 0; nt < 4; ++nt)
            acc2[nt] = (f32x4){b1v[nt], b1v[nt], b1v[nt], b1v[nt]};
#pragma unroll
        for (int ks = 0; ks < 2; ++ks) {
            const bf16x8 aH = *reinterpret_cast<const bf16x8*>(
                &h1w[((ks * 4 + g) * 16 + l15) * 8]);
#pragma unroll
            for (int nt = 0; nt < 4; ++nt)
                acc2[nt] = __builtin_amdgcn_mfma_f32_16x16x32_bf16(aH, w1g[ks][nt], acc2[nt], 0, 0, 0);
        }
#pragma unroll
        for (int nt = 0; nt < 4; ++nt) {
            const int h = nt * 16 + l15;
            const int kb = h >> 3, kk = h & 7;
#pragma unroll
            for (int r = 0; r < 4; ++r)
                h2w[(kb * 16 + 4 * g + r) * 8 + kk] = bf16r(fmaxf(acc2[nt][r], 0.f));
        }

        // GEMM-3: partial[16 a][32 i] = h2[16 a][K=64] @ G[64][32], store bf16
        f32x4 acc0 = {0.f, 0.f, 0.f, 0.f}, acc1 = {0.f, 0.f, 0.f, 0.f};
#pragma unroll
        for (int ks = 0; ks < 2; ++ks) {
            const bf16x8 aF = *reinterpret_cast<const bf16x8*>(
                &h2w[((ks * 4 + g) * 16 + l15) * 8]);
            acc0 = __builtin_amdgcn_mfma_f32_16x16x32_bf16(aF, bG[ks][0], acc0, 0, 0, 0);
            acc1 = __builtin_amdgcn_mfma_f32_16x16x32_bf16(aF, bG[ks][1], acc1, 0, 0, 0);
        }
        unsigned short* pp = partialb + ((size_t)(z * kN + bcol) * kN + m0) * kC;
#pragma unroll
        for (int r = 0; r < 4; ++r) {
            pp[(4 * g + r) * kC + l15]      = bf16r(acc0[r]);
            pp[(4 * g + r) * kC + 16 + l15] = bf16r(acc1[r]);
        }
    }
}

// ---------------- reduce: block=(z,a). out = (sum_b partial + b2@S) * mask / sqrt(n) ----------------
__global__ __launch_bounds__(256) void reduce_kernel(
    const unsigned short* __restrict__ partialb, // [z*kN + b][kN][kC] bf16
    const float* __restrict__ feat,      // [B*N, C] layer input (for S)
    const float* __restrict__ b2,        // [C*C] (layer-offset)
    const float* __restrict__ mask,      // [B, N]
    float* __restrict__ dst)             // [B, N, C]
{
    __shared__ float red[8][kC];
    __shared__ float redS[8][kC];
    __shared__ float Ssh[kC], Vsh[kC];

    const int tid = threadIdx.x;
    const int blk = blockIdx.x;              // z*kN + a
    const int z = blk / kN, a = blk - z * kN;
    const int i = tid & 31, s = tid >> 5;    // 8 slices x 32 i

    // fused: partial-sum over b AND S-sum over b, same loop
    float acc = 0.f, accS = 0.f;
    const unsigned short* pb =
        partialb + ((size_t)(z * kN + s * 24) * kN + a) * kC + i;
    const float* fb = feat + (size_t)(z * kN + s * 24) * kC + i;
#pragma unroll 4
    for (int q = 0; q < 24; ++q) {
        acc  += bf2f(pb[(size_t)q * kN * kC]);
        accS += fb[q * kC];
    }
    red[s][i] = acc;
    redS[s][i] = accS;
    __syncthreads();

    if (tid < kC) {
        float v = 0.f, sv = 0.f;
#pragma unroll
        for (int q = 0; q < 8; ++q) { v += red[q][tid]; sv += redS[q][tid]; }
        Vsh[tid] = v;
        Ssh[tid] = sv;
    }
    __syncthreads();

    if (tid < kC) {
        float bt = 0.f;
#pragma unroll
        for (int j = 0; j < kC; ++j) bt = fmaf(b2[tid * kC + j], Ssh[j], bt);
        dst[(size_t)blk * kC + tid] = (Vsh[tid] + bt) * kInvSqrtN * mask[z * kN + a];
    }
}

} // namespace

extern "C" void kernel_launch(void* const* d_in, const int* in_sizes, int n_in,
                              void* d_out, int out_size, void* d_ws, size_t ws_size,
                              hipStream_t stream) {
    const float* features = (const float*)d_in[0];
    const float* xyz      = (const float*)d_in[1];
    const float* mask     = (const float*)d_in[2];
    const float* W0       = (const float*)d_in[3];
    const float* b0       = (const float*)d_in[4];
    const float* W1       = (const float*)d_in[5];
    const float* b1       = (const float*)d_in[6];
    const float* W2       = (const float*)d_in[7];
    const float* b2       = (const float*)d_in[8];
    float* out = (float*)d_out;

    // workspace layout (float offsets):
    //   wb0     :       0 ..    2048   (4096 ushort  = 2 layers x 2048)
    //   wb1     :    2048 ..    6144   (8192 ushort  = 2 layers x 4096)
    //   partialb:    6144 .. 2365440   (2*192*192*32 ushort = 4.7MB)
    //   ftmp    : 2365440 .. 2377728
    float* ws = (float*)d_ws;
    unsigned short* wb0 = (unsigned short*)(ws);
    unsigned short* wb1 = (unsigned short*)(ws + 2048);
    unsigned short* partialb = (unsigned short*)(ws + 6144);
    float* ftmp = ws + 2365440;

    init_kernel<<<2, 256, 0, stream>>>(W0, W1, wb0, wb1);

    const float* cur = features;
    for (int l = 0; l < kLayers; ++l) {
        float* dst = (l == kLayers - 1) ? out : ftmp;
        fused_kernel<<<kB * kN, 256, 0, stream>>>(
            cur, W2 + (size_t)l * kH * kC * kC,
            b0 + (size_t)l * kH, b1 + (size_t)l * kH,
            xyz, wb0 + (size_t)l * 2048, wb1 + (size_t)l * 4096,
            partialb);
        reduce_kernel<<<kB * kN, 256, 0, stream>>>(
            partialb, cur, b2 + (size_t)l * kC * kC, mask, dst);
        cur = dst;
    }
}

// Round 12
// 60.522 us; speedup vs baseline: 1.5964x; 1.0328x over previous
//
#include <hip/hip_runtime.h>
#include <math.h>

namespace {

constexpr int kB  = 2;
constexpr int kN  = 192;
constexpr int kC  = 32;
constexpr int kH  = 64;
constexpr int kNB = 20;
constexpr int kLayers = 2;
constexpr float kInvSqrtN = 0.07216878364870323f;  // 1/sqrt(192)

typedef __attribute__((ext_vector_type(8))) short bf16x8;
typedef __attribute__((ext_vector_type(4))) float f32x4;

__device__ inline unsigned short bf16r(float x) {   // RNE f32->bf16
    unsigned int u = __float_as_uint(x);
    u = (u + 0x7FFFu + ((u >> 16) & 1u)) >> 16;
    return (unsigned short)u;
}
__device__ inline float bf2f(unsigned short v) {
    return __uint_as_float(((unsigned int)v) << 16);
}

// ---------------- init: packed W0/W1 frags only (2 blocks) ----------------
// wb0[l][kb=0..3][n=0..63][8]  (k = kb*8+i, zero-padded past kNB) -> 2048 ushort/layer
// wb1[l][kb=0..7][n=0..63][8]                                     -> 4096 ushort/layer
__global__ __launch_bounds__(256) void init_kernel(
    const float* __restrict__ W0,
    const float* __restrict__ W1,
    unsigned short* __restrict__ wb0,
    unsigned short* __restrict__ wb1)
{
    const int tid = threadIdx.x;
    if (blockIdx.x == 0) {
#pragma unroll
        for (int q = 0; q < 2; ++q) {
            const int grp = tid * 2 + q;                 // (l*4+kb)*64 + n
            const int l = grp >> 8, kb = (grp >> 6) & 3, n = grp & 63;
            union { bf16x8 v; unsigned short s[8]; } u;
#pragma unroll
            for (int i = 0; i < 8; ++i) {
                const int k = kb * 8 + i;
                u.s[i] = (k < kNB) ? bf16r(W0[(l * kNB + k) * kH + n]) : (unsigned short)0;
            }
            *reinterpret_cast<bf16x8*>(&wb0[(size_t)grp * 8]) = u.v;
        }
    } else {
#pragma unroll
        for (int q = 0; q < 4; ++q) {
            const int grp = tid * 4 + q;                 // (l*8+kb)*64 + n
            const int l = grp >> 9, kb = (grp >> 6) & 7, n = grp & 63;
            union { bf16x8 v; unsigned short s[8]; } u;
#pragma unroll
            for (int i = 0; i < 8; ++i) {
                const int k = kb * 8 + i;
                u.s[i] = bf16r(W1[(l * kH + k) * kH + n]);
            }
            *reinterpret_cast<bf16x8*>(&wb1[(size_t)grp * 8]) = u.v;
        }
    }
}

// ---------------- fused kernel: block = (z, bcol). 4 waves x 3 pipelined m-tiles. ----------------
// __launch_bounds__(256, 2): min 2 waves/EU -> VGPR cap 256 (grid is 384 blocks =
// 1.5/CU, so high per-wave ILP beats theoretical occupancy; at the default the
// compiler allocated 44 VGPRs and rematerialized all weight frags from L2 in-loop).
__global__ __launch_bounds__(256, 2) void fused_kernel(
    const float* __restrict__ feat,   // [B*N, C] layer input
    const float* __restrict__ W2,     // [H, C*C] (layer-offset)
    const float* __restrict__ b0,     // [H]
    const float* __restrict__ b1,     // [H]
    const float* __restrict__ xyz,    // [B,N,3]
    const unsigned short* __restrict__ wb0,   // layer-offset
    const unsigned short* __restrict__ wb1,   // layer-offset
    unsigned short* __restrict__ partialb)    // [z*kN + bcol][kN][kC] bf16
{
    __shared__ __align__(16) unsigned short Gs[8 * kC * 8];   // [kb8][i32][8]  4KB
    __shared__ __align__(16) unsigned short h1b[4][3][1024];  // per-wave, per-tile 24KB
    __shared__ __align__(16) unsigned short h2b[4][3][1024];  // per-wave, per-tile 24KB

    const int tid  = threadIdx.x;
    const int wave = tid >> 6, lane = tid & 63;
    const int g = lane >> 4, l15 = lane & 15;
    const int z = blockIdx.x / kN, bcol = blockIdx.x - z * kN;

    // wave-uniform feature row via scalar loads (no LDS, no barrier)
    const float* frow = feat + (size_t)(z * kN + bcol) * kC;
    float fr[kC];
#pragma unroll
    for (int j = 0; j < kC; ++j) fr[j] = frow[j];

    // --- phase A: G row for b=bcol into LDS ---
#pragma unroll
    for (int p = 0; p < 8; ++p) {
        const int idx = tid + 256 * p;          // 0..2047 = h*32+i
        const int h = idx >> 5, i = idx & 31;
        const float* w = W2 + h * (kC * kC) + i * kC;
        float s = 0.f;
#pragma unroll
        for (int j = 0; j < kC; j += 4) {
            const float4 w4 = *reinterpret_cast<const float4*>(&w[j]);
            s = fmaf(w4.x, fr[j], s);
            s = fmaf(w4.y, fr[j + 1], s);
            s = fmaf(w4.z, fr[j + 2], s);
            s = fmaf(w4.w, fr[j + 3], s);
        }
        Gs[((h >> 3) * kC + i) * 8 + (h & 7)] = bf16r(s);
    }

    // --- per-lane weight frags (pre-packed, L2 broadcast) ---
    bf16x8 w0g[4], w1g[2][4];
    float b0v[4], b1v[4];
#pragma unroll
    for (int nt = 0; nt < 4; ++nt) {
        const int n = nt * 16 + l15;
        w0g[nt] = *reinterpret_cast<const bf16x8*>(&wb0[((size_t)g * kH + n) * 8]);
        b0v[nt] = b0[n];
        b1v[nt] = b1[n];
    }
#pragma unroll
    for (int ks = 0; ks < 2; ++ks)
#pragma unroll
        for (int nt = 0; nt < 4; ++nt)
            w1g[ks][nt] = *reinterpret_cast<const bf16x8*>(
                &wb1[((size_t)(ks * 4 + g) * kH + nt * 16 + l15) * 8]);

    const float bx = xyz[(z * kN + bcol) * 3 + 0];
    const float by = xyz[(z * kN + bcol) * 3 + 1];
    const float bz = xyz[(z * kN + bcol) * 3 + 2];

    __syncthreads();   // Gs ready (only cross-wave dependency)

    // B-frags (G) in registers
    bf16x8 bG[2][2];
#pragma unroll
    for (int ks = 0; ks < 2; ++ks)
#pragma unroll
        for (int nt = 0; nt < 2; ++nt)
            bG[ks][nt] = *reinterpret_cast<const bf16x8*>(
                &Gs[((ks * 4 + g) * kC + nt * 16 + l15) * 8]);

    // --- pipelined per-tile loop: independent LDS slices per t ---
#pragma unroll
    for (int t = 0; t < 3; ++t) {
        const int m0 = (wave * 3 + t) * 16;
        unsigned short* h1w = h1b[wave][t];
        unsigned short* h2w = h2b[wave][t];

        // A-frag: rb for edge (arow = m0+l15, bcol), k = 8g+i, in-register
        const int arow = m0 + l15;
        const float dx = xyz[(z * kN + arow) * 3 + 0] - bx;
        const float dy = xyz[(z * kN + arow) * 3 + 1] - by;
        const float dz = xyz[(z * kN + arow) * 3 + 2] - bz;
        const float d  = sqrtf(fmaf(dx, dx, fmaf(dy, dy, fmaf(dz, dz, 1e-12f))));
        const float dn = d * (19.0f / 10.0f);   // y_k = clamp(dn - k, -1, 1)
        union { bf16x8 v; unsigned short s[8]; } aU;
#pragma unroll
        for (int i = 0; i < 8; ++i) {
            const float y = fminf(1.f, fmaxf(-1.f, dn - (float)(8 * g + i)));
            aU.s[i] = bf16r(__cosf(1.57079632679f * y));
        }
        const bf16x8 aR = aU.v;   // k>=20 entries hit zero-padded W0 frags

        // GEMM-1: h1[16 a][64 h] = rb[16 a][K=32] @ W0[32][64]
#pragma unroll
        for (int nt = 0; nt < 4; ++nt) {
            f32x4 acc = {b0v[nt], b0v[nt], b0v[nt], b0v[nt]};
            acc = __builtin_amdgcn_mfma_f32_16x16x32_bf16(aR, w0g[nt], acc, 0, 0, 0);
            const int h = nt * 16 + l15;
            const int kb = h >> 3, kk = h & 7;
#pragma unroll
            for (int r = 0; r < 4; ++r)
                h1w[(kb * 16 + 4 * g + r) * 8 + kk] = bf16r(fmaxf(acc[r], 0.f));
        }
        // wave-private h1 slice; same-wave LDS RAW ordered via lgkmcnt

        // GEMM-2: h2[16 a][64] = h1[16 a][K=64] @ W1[64][64]
        f32x4 acc2[4];
#pragma unroll
        for (int nt = 0; nt < 4; ++nt)
            acc2[nt] = (f32x4){b1v[nt], b1v[nt], b1v[nt], b1v[nt]};
#pragma unroll
        for (int ks = 0; ks < 2; ++ks) {
            const bf16x8 aH = *reinterpret_cast<const bf16x8*>(
                &h1w[((ks * 4 + g) * 16 + l15) * 8]);
#pragma unroll
            for (int nt = 0; nt < 4; ++nt)
                acc2[nt] = __builtin_amdgcn_mfma_f32_16x16x32_bf16(aH, w1g[ks][nt], acc2[nt], 0, 0, 0);
        }
#pragma unroll
        for (int nt = 0; nt < 4; ++nt) {
            const int h = nt * 16 + l15;
            const int kb = h >> 3, kk = h & 7;
#pragma unroll
            for (int r = 0; r < 4; ++r)
                h2w[(kb * 16 + 4 * g + r) * 8 + kk] = bf16r(fmaxf(acc2[nt][r], 0.f));
        }

        // GEMM-3: partial[16 a][32 i] = h2[16 a][K=64] @ G[64][32], store bf16
        f32x4 acc0 = {0.f, 0.f, 0.f, 0.f}, acc1 = {0.f, 0.f, 0.f, 0.f};
#pragma unroll
        for (int ks = 0; ks < 2; ++ks) {
            const bf16x8 aF = *reinterpret_cast<const bf16x8*>(
                &h2w[((ks * 4 + g) * 16 + l15) * 8]);
            acc0 = __builtin_amdgcn_mfma_f32_16x16x32_bf16(aF, bG[ks][0], acc0, 0, 0, 0);
            acc1 = __builtin_amdgcn_mfma_f32_16x16x32_bf16(aF, bG[ks][1], acc1, 0, 0, 0);
        }
        unsigned short* pp = partialb + ((size_t)(z * kN + bcol) * kN + m0) * kC;
#pragma unroll
        for (int r = 0; r < 4; ++r) {
            pp[(4 * g + r) * kC + l15]      = bf16r(acc0[r]);
            pp[(4 * g + r) * kC + 16 + l15] = bf16r(acc1[r]);
        }
    }
}

// ---------------- reduce: block=(z,a). out = (sum_b partial + b2@S) * mask / sqrt(n) ----------------
__global__ __launch_bounds__(256) void reduce_kernel(
    const unsigned short* __restrict__ partialb, // [z*kN + b][kN][kC] bf16
    const float* __restrict__ feat,      // [B*N, C] layer input (for S)
    const float* __restrict__ b2,        // [C*C] (layer-offset)
    const float* __restrict__ mask,      // [B, N]
    float* __restrict__ dst)             // [B, N, C]
{
    __shared__ float red[8][kC];
    __shared__ float redS[8][kC];
    __shared__ float Ssh[kC], Vsh[kC];

    const int tid = threadIdx.x;
    const int blk = blockIdx.x;              // z*kN + a
    const int z = blk / kN, a = blk - z * kN;
    const int i = tid & 31, s = tid >> 5;    // 8 slices x 32 i

    // fused: partial-sum over b AND S-sum over b, same loop
    float acc = 0.f, accS = 0.f;
    const unsigned short* pb =
        partialb + ((size_t)(z * kN + s * 24) * kN + a) * kC + i;
    const float* fb = feat + (size_t)(z * kN + s * 24) * kC + i;
#pragma unroll 4
    for (int q = 0; q < 24; ++q) {
        acc  += bf2f(pb[(size_t)q * kN * kC]);
        accS += fb[q * kC];
    }
    red[s][i] = acc;
    redS[s][i] = accS;
    __syncthreads();

    if (tid < kC) {
        float v = 0.f, sv = 0.f;
#pragma unroll
        for (int q = 0; q < 8; ++q) { v += red[q][tid]; sv += redS[q][tid]; }
        Vsh[tid] = v;
        Ssh[tid] = sv;
    }
    __syncthreads();

    if (tid < kC) {
        float bt = 0.f;
#pragma unroll
        for (int j = 0; j < kC; ++j) bt = fmaf(b2[tid * kC + j], Ssh[j], bt);
        dst[(size_t)blk * kC + tid] = (Vsh[tid] + bt) * kInvSqrtN * mask[z * kN + a];
    }
}

} // namespace

extern "C" void kernel_launch(void* const* d_in, const int* in_sizes, int n_in,
                              void* d_out, int out_size, void* d_ws, size_t ws_size,
                              hipStream_t stream) {
    const float* features = (const float*)d_in[0];
    const float* xyz      = (const float*)d_in[1];
    const float* mask     = (const float*)d_in[2];
    const float* W0       = (const float*)d_in[3];
    const float* b0       = (const float*)d_in[4];
    const float* W1       = (const float*)d_in[5];
    const float* b1       = (const float*)d_in[6];
    const float* W2       = (const float*)d_in[7];
    const float* b2       = (const float*)d_in[8];
    float* out = (float*)d_out;

    // workspace layout (float offsets):
    //   wb0     :       0 ..    2048   (4096 ushort  = 2 layers x 2048)
    //   wb1     :    2048 ..    6144   (8192 ushort  = 2 layers x 4096)
    //   partialb:    6144 .. 2365440   (2*192*192*32 ushort = 4.7MB)
    //   ftmp    : 2365440 .. 2377728
    float* ws = (float*)d_ws;
    unsigned short* wb0 = (unsigned short*)(ws);
    unsigned short* wb1 = (unsigned short*)(ws + 2048);
    unsigned short* partialb = (unsigned short*)(ws + 6144);
    float* ftmp = ws + 2365440;

    init_kernel<<<2, 256, 0, stream>>>(W0, W1, wb0, wb1);

    const float* cur = features;
    for (int l = 0; l < kLayers; ++l) {
        float* dst = (l == kLayers - 1) ? out : ftmp;
        fused_kernel<<<kB * kN, 256, 0, stream>>>(
            cur, W2 + (size_t)l * kH * kC * kC,
            b0 + (size_t)l * kH, b1 + (size_t)l * kH,
            xyz, wb0 + (size_t)l * 2048, wb1 + (size_t)l * 4096,
            partialb);
        reduce_kernel<<<kB * kN, 256, 0, stream>>>(
            partialb, cur, b2 + (size_t)l * kC * kC, mask, dst);
        cur = dst;
    }
}

// Round 13
// 59.437 us; speedup vs baseline: 1.6256x; 1.0183x over previous
//
#include <hip/hip_runtime.h>
#include <math.h>

namespace {

constexpr int kB  = 2;
constexpr int kN  = 192;
constexpr int kC  = 32;
constexpr int kH  = 64;
constexpr int kNB = 20;
constexpr int kLayers = 2;
constexpr float kInvSqrtN = 0.07216878364870323f;  // 1/sqrt(192)

typedef __attribute__((ext_vector_type(8))) short bf16x8;
typedef __attribute__((ext_vector_type(4))) float f32x4;

__device__ inline unsigned short bf16r(float x) {   // RNE f32->bf16
    unsigned int u = __float_as_uint(x);
    u = (u + 0x7FFFu + ((u >> 16) & 1u)) >> 16;
    return (unsigned short)u;
}
__device__ inline unsigned int bf16pk(float lo, float hi) {
    return (unsigned int)bf16r(lo) | ((unsigned int)bf16r(hi) << 16);
}
__device__ inline float bf2f(unsigned short v) {
    return __uint_as_float(((unsigned int)v) << 16);
}

// ---------------- init: packed W0/W1 frags only (2 blocks) ----------------
// wb0[l][kb=0..3][n=0..63][8]  (k = kb*8+i, zero-padded past kNB) -> 2048 ushort/layer
// wb1[l][kb=0..7][n=0..63][8]                                     -> 4096 ushort/layer
__global__ __launch_bounds__(256) void init_kernel(
    const float* __restrict__ W0,
    const float* __restrict__ W1,
    unsigned short* __restrict__ wb0,
    unsigned short* __restrict__ wb1)
{
    const int tid = threadIdx.x;
    if (blockIdx.x == 0) {
#pragma unroll
        for (int q = 0; q < 2; ++q) {
            const int grp = tid * 2 + q;                 // (l*4+kb)*64 + n
            const int l = grp >> 8, kb = (grp >> 6) & 3, n = grp & 63;
            union { bf16x8 v; unsigned short s[8]; } u;
#pragma unroll
            for (int i = 0; i < 8; ++i) {
                const int k = kb * 8 + i;
                u.s[i] = (k < kNB) ? bf16r(W0[(l * kNB + k) * kH + n]) : (unsigned short)0;
            }
            *reinterpret_cast<bf16x8*>(&wb0[(size_t)grp * 8]) = u.v;
        }
    } else {
#pragma unroll
        for (int q = 0; q < 4; ++q) {
            const int grp = tid * 4 + q;                 // (l*8+kb)*64 + n
            const int l = grp >> 9, kb = (grp >> 6) & 7, n = grp & 63;
            union { bf16x8 v; unsigned short s[8]; } u;
#pragma unroll
            for (int i = 0; i < 8; ++i) {
                const int k = kb * 8 + i;
                u.s[i] = bf16r(W1[(l * kH + k) * kH + n]);
            }
            *reinterpret_cast<bf16x8*>(&wb1[(size_t)grp * 8]) = u.v;
        }
    }
}

// ---------------- fused kernel: block = (z, bcol). 4 waves x 3 pipelined m-tiles. ----------------
// GEMM-3 uses SWAPPED operands (A=G-frag, B=h2-frag; frag lane layouts are
// symmetric and share sigma(k), so D[i][a] = out[a][i]) -> each lane holds 4
// consecutive i -> 2x coalesced 8B stores instead of 8x scattered 2B stores.
__global__ __launch_bounds__(256, 2) void fused_kernel(
    const float* __restrict__ feat,   // [B*N, C] layer input
    const float* __restrict__ W2,     // [H, C*C] (layer-offset)
    const float* __restrict__ b0,     // [H]
    const float* __restrict__ b1,     // [H]
    const float* __restrict__ xyz,    // [B,N,3]
    const unsigned short* __restrict__ wb0,   // layer-offset
    const unsigned short* __restrict__ wb1,   // layer-offset
    unsigned short* __restrict__ partialb)    // [z*kN + bcol][kN][kC] bf16
{
    __shared__ __align__(16) unsigned short Gs[8 * kC * 8];   // [kb8][i32][8]  4KB
    __shared__ __align__(16) unsigned short h1b[4][3][1024];  // per-wave, per-tile 24KB
    __shared__ __align__(16) unsigned short h2b[4][3][1024];  // per-wave, per-tile 24KB

    const int tid  = threadIdx.x;
    const int wave = tid >> 6, lane = tid & 63;
    const int g = lane >> 4, l15 = lane & 15;
    const int z = blockIdx.x / kN, bcol = blockIdx.x - z * kN;

    // wave-uniform feature row via scalar loads (no LDS, no barrier)
    const float* frow = feat + (size_t)(z * kN + bcol) * kC;
    float fr[kC];
#pragma unroll
    for (int j = 0; j < kC; ++j) fr[j] = frow[j];

    // --- phase A: G row for b=bcol into LDS ---
#pragma unroll
    for (int p = 0; p < 8; ++p) {
        const int idx = tid + 256 * p;          // 0..2047 = h*32+i
        const int h = idx >> 5, i = idx & 31;
        const float* w = W2 + h * (kC * kC) + i * kC;
        float s = 0.f;
#pragma unroll
        for (int j = 0; j < kC; j += 4) {
            const float4 w4 = *reinterpret_cast<const float4*>(&w[j]);
            s = fmaf(w4.x, fr[j], s);
            s = fmaf(w4.y, fr[j + 1], s);
            s = fmaf(w4.z, fr[j + 2], s);
            s = fmaf(w4.w, fr[j + 3], s);
        }
        Gs[((h >> 3) * kC + i) * 8 + (h & 7)] = bf16r(s);
    }

    // --- per-lane weight frags (pre-packed, L2 broadcast) ---
    bf16x8 w0g[4], w1g[2][4];
    float b0v[4], b1v[4];
#pragma unroll
    for (int nt = 0; nt < 4; ++nt) {
        const int n = nt * 16 + l15;
        w0g[nt] = *reinterpret_cast<const bf16x8*>(&wb0[((size_t)g * kH + n) * 8]);
        b0v[nt] = b0[n];
        b1v[nt] = b1[n];
    }
#pragma unroll
    for (int ks = 0; ks < 2; ++ks)
#pragma unroll
        for (int nt = 0; nt < 4; ++nt)
            w1g[ks][nt] = *reinterpret_cast<const bf16x8*>(
                &wb1[((size_t)(ks * 4 + g) * kH + nt * 16 + l15) * 8]);

    const float bx = xyz[(z * kN + bcol) * 3 + 0];
    const float by = xyz[(z * kN + bcol) * 3 + 1];
    const float bz = xyz[(z * kN + bcol) * 3 + 2];

    __syncthreads();   // Gs ready (only cross-wave dependency)

    // G frags in registers (used as A-operand in swapped GEMM-3)
    bf16x8 bG[2][2];
#pragma unroll
    for (int ks = 0; ks < 2; ++ks)
#pragma unroll
        for (int mi = 0; mi < 2; ++mi)
            bG[ks][mi] = *reinterpret_cast<const bf16x8*>(
                &Gs[((ks * 4 + g) * kC + mi * 16 + l15) * 8]);

    // --- pipelined per-tile loop: independent LDS slices per t ---
#pragma unroll
    for (int t = 0; t < 3; ++t) {
        const int m0 = (wave * 3 + t) * 16;
        unsigned short* h1w = h1b[wave][t];
        unsigned short* h2w = h2b[wave][t];

        // A-frag: rb for edge (arow = m0+l15, bcol), k = 8g+i, in-register
        const int arow = m0 + l15;
        const float dx = xyz[(z * kN + arow) * 3 + 0] - bx;
        const float dy = xyz[(z * kN + arow) * 3 + 1] - by;
        const float dz = xyz[(z * kN + arow) * 3 + 2] - bz;
        const float d  = sqrtf(fmaf(dx, dx, fmaf(dy, dy, fmaf(dz, dz, 1e-12f))));
        const float dn = d * (19.0f / 10.0f);   // y_k = clamp(dn - k, -1, 1)
        union { bf16x8 v; unsigned short s[8]; } aU;
#pragma unroll
        for (int i = 0; i < 8; ++i) {
            const float y = fminf(1.f, fmaxf(-1.f, dn - (float)(8 * g + i)));
            aU.s[i] = bf16r(__cosf(1.57079632679f * y));
        }
        const bf16x8 aR = aU.v;   // k>=20 entries hit zero-padded W0 frags

        // GEMM-1: h1[16 a][64 h] = rb[16 a][K=32] @ W0[32][64]
#pragma unroll
        for (int nt = 0; nt < 4; ++nt) {
            f32x4 acc = {b0v[nt], b0v[nt], b0v[nt], b0v[nt]};
            acc = __builtin_amdgcn_mfma_f32_16x16x32_bf16(aR, w0g[nt], acc, 0, 0, 0);
            const int h = nt * 16 + l15;
            const int kb = h >> 3, kk = h & 7;
#pragma unroll
            for (int r = 0; r < 4; ++r)
                h1w[(kb * 16 + 4 * g + r) * 8 + kk] = bf16r(fmaxf(acc[r], 0.f));
        }
        // wave-private h1 slice; same-wave LDS RAW ordered via lgkmcnt

        // GEMM-2: h2[16 a][64] = h1[16 a][K=64] @ W1[64][64]
        f32x4 acc2[4];
#pragma unroll
        for (int nt = 0; nt < 4; ++nt)
            acc2[nt] = (f32x4){b1v[nt], b1v[nt], b1v[nt], b1v[nt]};
#pragma unroll
        for (int ks = 0; ks < 2; ++ks) {
            const bf16x8 aH = *reinterpret_cast<const bf16x8*>(
                &h1w[((ks * 4 + g) * 16 + l15) * 8]);
#pragma unroll
            for (int nt = 0; nt < 4; ++nt)
                acc2[nt] = __builtin_amdgcn_mfma_f32_16x16x32_bf16(aH, w1g[ks][nt], acc2[nt], 0, 0, 0);
        }
#pragma unroll
        for (int nt = 0; nt < 4; ++nt) {
            const int h = nt * 16 + l15;
            const int kb = h >> 3, kk = h & 7;
#pragma unroll
            for (int r = 0; r < 4; ++r)
                h2w[(kb * 16 + 4 * g + r) * 8 + kk] = bf16r(fmaxf(acc2[nt][r], 0.f));
        }

        // GEMM-3 (swapped): D[i][a] = G^T . h2^T  ->  lane holds out[a0+l15][mi*16+4g+0..3]
        f32x4 accS0 = {0.f, 0.f, 0.f, 0.f}, accS1 = {0.f, 0.f, 0.f, 0.f};
#pragma unroll
        for (int ks = 0; ks < 2; ++ks) {
            const bf16x8 aF = *reinterpret_cast<const bf16x8*>(
                &h2w[((ks * 4 + g) * 16 + l15) * 8]);
            accS0 = __builtin_amdgcn_mfma_f32_16x16x32_bf16(bG[ks][0], aF, accS0, 0, 0, 0);
            accS1 = __builtin_amdgcn_mfma_f32_16x16x32_bf16(bG[ks][1], aF, accS1, 0, 0, 0);
        }
        unsigned short* pp =
            partialb + ((size_t)(z * kN + bcol) * kN + m0 + l15) * kC + 4 * g;
        uint2 st0, st1;
        st0.x = bf16pk(accS0[0], accS0[1]);
        st0.y = bf16pk(accS0[2], accS0[3]);
        st1.x = bf16pk(accS1[0], accS1[1]);
        st1.y = bf16pk(accS1[2], accS1[3]);
        *reinterpret_cast<uint2*>(pp)      = st0;   // i = 4g .. 4g+3
        *reinterpret_cast<uint2*>(pp + 16) = st1;   // i = 16+4g .. 16+4g+3
    }
}

// ---------------- reduce: block=(z,a). out = (sum_b partial + b2@S) * mask / sqrt(n) ----------------
// Vectorized: u32 loads (2 bf16) / float2 loads; 16 b-slices x 16 i-pairs.
__global__ __launch_bounds__(256) void reduce_kernel(
    const unsigned short* __restrict__ partialb, // [z*kN + b][kN][kC] bf16
    const float* __restrict__ feat,      // [B*N, C] layer input (for S)
    const float* __restrict__ b2,        // [C*C] (layer-offset)
    const float* __restrict__ mask,      // [B, N]
    float* __restrict__ dst)             // [B, N, C]
{
    __shared__ float redV[16][kC];
    __shared__ float redS[16][kC];
    __shared__ float Ssh[kC], Vsh[kC];

    const int tid = threadIdx.x;
    const int blk = blockIdx.x;              // z*kN + a
    const int z = blk / kN, a = blk - z * kN;
    const int u = tid & 15;                  // i-pair: i = 2u, 2u+1
    const int s = tid >> 4;                  // 16 b-slices of 12

    float a0 = 0.f, a1 = 0.f, s0 = 0.f, s1 = 0.f;
    const unsigned int* pb = reinterpret_cast<const unsigned int*>(
        partialb + ((size_t)(z * kN + s * 12) * kN + a) * kC) + u;
    const float2* fb = reinterpret_cast<const float2*>(
        feat + (size_t)(z * kN + s * 12) * kC) + u;
#pragma unroll 4
    for (int q = 0; q < 12; ++q) {
        const unsigned int w = pb[(size_t)q * kN * (kC / 2)];
        a0 += bf2f((unsigned short)(w & 0xffffu));
        a1 += bf2f((unsigned short)(w >> 16));
        const float2 f2 = fb[q * (kC / 2)];
        s0 += f2.x; s1 += f2.y;
    }
    redV[s][2 * u]     = a0;
    redV[s][2 * u + 1] = a1;
    redS[s][2 * u]     = s0;
    redS[s][2 * u + 1] = s1;
    __syncthreads();

    if (tid < kC) {
        float v = 0.f, sv = 0.f;
#pragma unroll
        for (int q = 0; q < 16; ++q) { v += redV[q][tid]; sv += redS[q][tid]; }
        Vsh[tid] = v;
        Ssh[tid] = sv;
    }
    __syncthreads();

    if (tid < kC) {
        float bt = 0.f;
#pragma unroll
        for (int j = 0; j < kC; ++j) bt = fmaf(b2[tid * kC + j], Ssh[j], bt);
        dst[(size_t)blk * kC + tid] = (Vsh[tid] + bt) * kInvSqrtN * mask[z * kN + a];
    }
}

} // namespace

extern "C" void kernel_launch(void* const* d_in, const int* in_sizes, int n_in,
                              void* d_out, int out_size, void* d_ws, size_t ws_size,
                              hipStream_t stream) {
    const float* features = (const float*)d_in[0];
    const float* xyz      = (const float*)d_in[1];
    const float* mask     = (const float*)d_in[2];
    const float* W0       = (const float*)d_in[3];
    const float* b0       = (const float*)d_in[4];
    const float* W1       = (const float*)d_in[5];
    const float* b1       = (const float*)d_in[6];
    const float* W2       = (const float*)d_in[7];
    const float* b2       = (const float*)d_in[8];
    float* out = (float*)d_out;

    // workspace layout (float offsets):
    //   wb0     :       0 ..    2048   (4096 ushort  = 2 layers x 2048)
    //   wb1     :    2048 ..    6144   (8192 ushort  = 2 layers x 4096)
    //   partialb:    6144 .. 2365440   (2*192*192*32 ushort = 4.7MB)
    //   ftmp    : 2365440 .. 2377728
    float* ws = (float*)d_ws;
    unsigned short* wb0 = (unsigned short*)(ws);
    unsigned short* wb1 = (unsigned short*)(ws + 2048);
    unsigned short* partialb = (unsigned short*)(ws + 6144);
    float* ftmp = ws + 2365440;

    init_kernel<<<2, 256, 0, stream>>>(W0, W1, wb0, wb1);

    const float* cur = features;
    for (int l = 0; l < kLayers; ++l) {
        float* dst = (l == kLayers - 1) ? out : ftmp;
        fused_kernel<<<kB * kN, 256, 0, stream>>>(
            cur, W2 + (size_t)l * kH * kC * kC,
            b0 + (size_t)l * kH, b1 + (size_t)l * kH,
            xyz, wb0 + (size_t)l * 2048, wb1 + (size_t)l * 4096,
            partialb);
        reduce_kernel<<<kB * kN, 256, 0, stream>>>(
            partialb, cur, b2 + (size_t)l * kC * kC, mask, dst);
        cur = dst;
    }
}

// Round 15
// 45.803 us; speedup vs baseline: 2.1095x; 1.2977x over previous
//
#include <hip/hip_runtime.h>
#include <math.h>

namespace {

constexpr int kB  = 2;
constexpr int kN  = 192;
constexpr int kC  = 32;
constexpr int kH  = 64;
constexpr int kNB = 20;
constexpr int kLayers = 2;
constexpr float kInvSqrtN = 0.07216878364870323f;  // 1/sqrt(192)

typedef __attribute__((ext_vector_type(8))) short bf16x8;
typedef __attribute__((ext_vector_type(4))) float f32x4;

__device__ inline unsigned short bf16r(float x) {   // RNE f32->bf16
    unsigned int u = __float_as_uint(x);
    u = (u + 0x7FFFu + ((u >> 16) & 1u)) >> 16;
    return (unsigned short)u;
}
__device__ inline unsigned int bf16pk(float lo, float hi) {
    return (unsigned int)bf16r(lo) | ((unsigned int)bf16r(hi) << 16);
}
__device__ inline float bf2f(unsigned short v) {
    return __uint_as_float(((unsigned int)v) << 16);
}

// ---- G rows via MFMA: one wave per (z,h): G_h[b][i] = feat[b][:] @ W2_h^T ----
// i spans kC=32 = TWO 16-wide N-tiles (ni=0,1).  [round-14 bug: only ni=0 was computed]
// Writes Gb[(z*kN+b)*2048 + (h>>3)*256 + i*8 + (h&7)]  (frag layout the fused kernel reads).
__device__ inline void g_rows(const float* __restrict__ featz,  // [kN][kC] for this z
                              const float* __restrict__ W2,     // [kH][kC*kC] layer base
                              int z, int h, int lane,
                              unsigned short* __restrict__ Gb)
{
    const int g = lane >> 4, l15 = lane & 15;
    // B-frags: B[k=j][n=i] = W2[h][i*32 + j]; lane covers 8 consecutive j
    union { bf16x8 v; unsigned short s[8]; } bu0, bu1;
    {
        const float* w0src = W2 + h * (kC * kC) + l15 * kC + 8 * g;
        const float* w1src = W2 + h * (kC * kC) + (16 + l15) * kC + 8 * g;
#pragma unroll
        for (int jj = 0; jj < 8; ++jj) {
            bu0.s[jj] = bf16r(w0src[jj]);
            bu1.s[jj] = bf16r(w1src[jj]);
        }
    }

    const int kb = h >> 3, kk = h & 7;
#pragma unroll
    for (int mt = 0; mt < kN / 16; ++mt) {
        const int b0 = mt * 16;
        // A-frag: A[m=b][k=j] = feat[b][j]; lane covers 8 consecutive j (coalesced)
        const float* asrc = featz + (b0 + l15) * kC + 8 * g;
        union { bf16x8 v; unsigned short s[8]; } au;
#pragma unroll
        for (int jj = 0; jj < 8; ++jj) au.s[jj] = bf16r(asrc[jj]);
        f32x4 acc0 = {0.f, 0.f, 0.f, 0.f};
        f32x4 acc1 = {0.f, 0.f, 0.f, 0.f};
        acc0 = __builtin_amdgcn_mfma_f32_16x16x32_bf16(au.v, bu0.v, acc0, 0, 0, 0);
        acc1 = __builtin_amdgcn_mfma_f32_16x16x32_bf16(au.v, bu1.v, acc1, 0, 0, 0);
        // D: col=l15 (=i within tile), row=4g+r (=b-local)
#pragma unroll
        for (int r = 0; r < 4; ++r) {
            const int b = b0 + 4 * g + r;
            const size_t base = ((size_t)(z * kN + b) * 8 + kb) * (kC * 8);
            Gb[base + l15 * 8 + kk]        = bf16r(acc0[r]);   // i = l15
            Gb[base + (16 + l15) * 8 + kk] = bf16r(acc1[r]);   // i = 16+l15
        }
    }
}

// ---------------- init: weight-frag packing (blocks 0,1) + layer-0 G (blocks 2..33) ----------------
// wb0[l][kb=0..3][n=0..63][8]  (k = kb*8+i, zero-padded past kNB) -> 2048 ushort/layer
// wb1[l][kb=0..7][n=0..63][8]                                     -> 4096 ushort/layer
__global__ __launch_bounds__(256) void init_kernel(
    const float* __restrict__ W0,
    const float* __restrict__ W1,
    const float* __restrict__ features,   // layer-0 feat
    const float* __restrict__ W2l0,       // layer-0 W2
    unsigned short* __restrict__ wb0,
    unsigned short* __restrict__ wb1,
    unsigned short* __restrict__ Gb)
{
    const int tid = threadIdx.x;
    if (blockIdx.x == 0) {
#pragma unroll
        for (int q = 0; q < 2; ++q) {
            const int grp = tid * 2 + q;                 // (l*4+kb)*64 + n
            const int l = grp >> 8, kb = (grp >> 6) & 3, n = grp & 63;
            union { bf16x8 v; unsigned short s[8]; } u;
#pragma unroll
            for (int i = 0; i < 8; ++i) {
                const int k = kb * 8 + i;
                u.s[i] = (k < kNB) ? bf16r(W0[(l * kNB + k) * kH + n]) : (unsigned short)0;
            }
            *reinterpret_cast<bf16x8*>(&wb0[(size_t)grp * 8]) = u.v;
        }
    } else if (blockIdx.x == 1) {
#pragma unroll
        for (int q = 0; q < 4; ++q) {
            const int grp = tid * 4 + q;                 // (l*8+kb)*64 + n
            const int l = grp >> 9, kb = (grp >> 6) & 7, n = grp & 63;
            union { bf16x8 v; unsigned short s[8]; } u;
#pragma unroll
            for (int i = 0; i < 8; ++i) {
                const int k = kb * 8 + i;
                u.s[i] = bf16r(W1[(l * kH + k) * kH + n]);
            }
            *reinterpret_cast<bf16x8*>(&wb1[(size_t)grp * 8]) = u.v;
        }
    } else {
        const int wave = tid >> 6, lane = tid & 63;
        const int pair = (blockIdx.x - 2) * 4 + wave;    // 0..127
        const int z = pair >> 6, h = pair & 63;
        g_rows(features + (size_t)z * kN * kC, W2l0, z, h, lane, Gb);
    }
}

// ---------------- g_kernel: G for one layer (feat from previous layer's output) ----------------
__global__ __launch_bounds__(256) void g_kernel(
    const float* __restrict__ feat,
    const float* __restrict__ W2,     // layer base
    unsigned short* __restrict__ Gb)
{
    const int wave = threadIdx.x >> 6, lane = threadIdx.x & 63;
    const int pair = blockIdx.x * 4 + wave;              // 0..127
    const int z = pair >> 6, h = pair & 63;
    g_rows(feat + (size_t)z * kN * kC, W2, z, h, lane, Gb);
}

// ---------------- fused kernel: block = (z, bcol). 4 waves x 3 m-tiles. ZERO barriers. ----------------
// h2[a, bcol*64+h] for all 192 a via MFMA MLP (wave-private LDS), then
// GEMM-3 swapped (A=G-frag, B=h2-frag -> D[i][a]) -> coalesced 8B partial stores.
__global__ __launch_bounds__(256, 2) void fused_kernel(
    const float* __restrict__ b0,     // [H]
    const float* __restrict__ b1,     // [H]
    const float* __restrict__ xyz,    // [B,N,3]
    const unsigned short* __restrict__ wb0,   // layer-offset
    const unsigned short* __restrict__ wb1,   // layer-offset
    const unsigned short* __restrict__ Gb,    // [z*kN+b][2048] frag layout
    unsigned short* __restrict__ partialb)    // [z*kN + bcol][kN][kC] bf16
{
    __shared__ __align__(16) unsigned short h1b[4][3][1024];  // per-wave, per-tile 24KB
    __shared__ __align__(16) unsigned short h2b[4][3][1024];  // per-wave, per-tile 24KB

    const int tid  = threadIdx.x;
    const int wave = tid >> 6, lane = tid & 63;
    const int g = lane >> 4, l15 = lane & 15;
    const int z = blockIdx.x / kN, bcol = blockIdx.x - z * kN;

    // --- per-lane weight frags (pre-packed, L2 broadcast) ---
    bf16x8 w0g[4], w1g[2][4];
    float b0v[4], b1v[4];
#pragma unroll
    for (int nt = 0; nt < 4; ++nt) {
        const int n = nt * 16 + l15;
        w0g[nt] = *reinterpret_cast<const bf16x8*>(&wb0[((size_t)g * kH + n) * 8]);
        b0v[nt] = b0[n];
        b1v[nt] = b1[n];
    }
#pragma unroll
    for (int ks = 0; ks < 2; ++ks)
#pragma unroll
        for (int nt = 0; nt < 4; ++nt)
            w1g[ks][nt] = *reinterpret_cast<const bf16x8*>(
                &wb1[((size_t)(ks * 4 + g) * kH + nt * 16 + l15) * 8]);

    // --- G frags from global (4KB row, L2-hot, lane-contiguous) ---
    const unsigned short* gRow = Gb + (size_t)(z * kN + bcol) * 2048;
    bf16x8 bG[2][2];
#pragma unroll
    for (int ks = 0; ks < 2; ++ks)
#pragma unroll
        for (int mi = 0; mi < 2; ++mi)
            bG[ks][mi] = *reinterpret_cast<const bf16x8*>(
                &gRow[((ks * 4 + g) * kC + mi * 16 + l15) * 8]);

    const float bx = xyz[(z * kN + bcol) * 3 + 0];
    const float by = xyz[(z * kN + bcol) * 3 + 1];
    const float bz = xyz[(z * kN + bcol) * 3 + 2];

    // --- pipelined per-tile loop: independent wave-private LDS slices per t ---
#pragma unroll
    for (int t = 0; t < 3; ++t) {
        const int m0 = (wave * 3 + t) * 16;
        unsigned short* h1w = h1b[wave][t];
        unsigned short* h2w = h2b[wave][t];

        // A-frag: rb for edge (arow = m0+l15, bcol), k = 8g+i, in-register
        const int arow = m0 + l15;
        const float dx = xyz[(z * kN + arow) * 3 + 0] - bx;
        const float dy = xyz[(z * kN + arow) * 3 + 1] - by;
        const float dz = xyz[(z * kN + arow) * 3 + 2] - bz;
        const float d  = sqrtf(fmaf(dx, dx, fmaf(dy, dy, fmaf(dz, dz, 1e-12f))));
        const float dn = d * (19.0f / 10.0f);   // y_k = clamp(dn - k, -1, 1)
        union { bf16x8 v; unsigned short s[8]; } aU;
#pragma unroll
        for (int i = 0; i < 8; ++i) {
            const float y = fminf(1.f, fmaxf(-1.f, dn - (float)(8 * g + i)));
            aU.s[i] = bf16r(__cosf(1.57079632679f * y));
        }
        const bf16x8 aR = aU.v;   // k>=20 entries hit zero-padded W0 frags

        // GEMM-1: h1[16 a][64 h] = rb[16 a][K=32] @ W0[32][64]
#pragma unroll
        for (int nt = 0; nt < 4; ++nt) {
            f32x4 acc = {b0v[nt], b0v[nt], b0v[nt], b0v[nt]};
            acc = __builtin_amdgcn_mfma_f32_16x16x32_bf16(aR, w0g[nt], acc, 0, 0, 0);
            const int h = nt * 16 + l15;
            const int kb = h >> 3, kk = h & 7;
#pragma unroll
            for (int r = 0; r < 4; ++r)
                h1w[(kb * 16 + 4 * g + r) * 8 + kk] = bf16r(fmaxf(acc[r], 0.f));
        }
        // wave-private h1 slice; same-wave LDS RAW ordered via lgkmcnt

        // GEMM-2: h2[16 a][64] = h1[16 a][K=64] @ W1[64][64]
        f32x4 acc2[4];
#pragma unroll
        for (int nt = 0; nt < 4; ++nt)
            acc2[nt] = (f32x4){b1v[nt], b1v[nt], b1v[nt], b1v[nt]};
#pragma unroll
        for (int ks = 0; ks < 2; ++ks) {
            const bf16x8 aH = *reinterpret_cast<const bf16x8*>(
                &h1w[((ks * 4 + g) * 16 + l15) * 8]);
#pragma unroll
            for (int nt = 0; nt < 4; ++nt)
                acc2[nt] = __builtin_amdgcn_mfma_f32_16x16x32_bf16(aH, w1g[ks][nt], acc2[nt], 0, 0, 0);
        }
#pragma unroll
        for (int nt = 0; nt < 4; ++nt) {
            const int h = nt * 16 + l15;
            const int kb = h >> 3, kk = h & 7;
#pragma unroll
            for (int r = 0; r < 4; ++r)
                h2w[(kb * 16 + 4 * g + r) * 8 + kk] = bf16r(fmaxf(acc2[nt][r], 0.f));
        }

        // GEMM-3 (swapped): D[i][a] -> lane holds out[m0+l15][mi*16+4g+0..3]
        f32x4 accS0 = {0.f, 0.f, 0.f, 0.f}, accS1 = {0.f, 0.f, 0.f, 0.f};
#pragma unroll
        for (int ks = 0; ks < 2; ++ks) {
            const bf16x8 aF = *reinterpret_cast<const bf16x8*>(
                &h2w[((ks * 4 + g) * 16 + l15) * 8]);
            accS0 = __builtin_amdgcn_mfma_f32_16x16x32_bf16(bG[ks][0], aF, accS0, 0, 0, 0);
            accS1 = __builtin_amdgcn_mfma_f32_16x16x32_bf16(bG[ks][1], aF, accS1, 0, 0, 0);
        }
        unsigned short* pp =
            partialb + ((size_t)(z * kN + bcol) * kN + m0 + l15) * kC + 4 * g;
        uint2 st0, st1;
        st0.x = bf16pk(accS0[0], accS0[1]);
        st0.y = bf16pk(accS0[2], accS0[3]);
        st1.x = bf16pk(accS1[0], accS1[1]);
        st1.y = bf16pk(accS1[2], accS1[3]);
        *reinterpret_cast<uint2*>(pp)      = st0;   // i = 4g .. 4g+3
        *reinterpret_cast<uint2*>(pp + 16) = st1;   // i = 16+4g .. 16+4g+3
    }
}

// ---------------- reduce: block=(z,a). out = (sum_b partial + b2@S) * mask / sqrt(n) ----------------
__global__ __launch_bounds__(256) void reduce_kernel(
    const unsigned short* __restrict__ partialb, // [z*kN + b][kN][kC] bf16
    const float* __restrict__ feat,      // [B*N, C] layer input (for S)
    const float* __restrict__ b2,        // [C*C] (layer-offset)
    const float* __restrict__ mask,      // [B, N]
    float* __restrict__ dst)             // [B, N, C]
{
    __shared__ float redV[16][kC];
    __shared__ float redS[16][kC];
    __shared__ float Ssh[kC], Vsh[kC];

    const int tid = threadIdx.x;
    const int blk = blockIdx.x;              // z*kN + a
    const int z = blk / kN, a = blk - z * kN;
    const int u = tid & 15;                  // i-pair: i = 2u, 2u+1
    const int s = tid >> 4;                  // 16 b-slices of 12

    float a0 = 0.f, a1 = 0.f, s0 = 0.f, s1 = 0.f;
    const unsigned int* pb = reinterpret_cast<const unsigned int*>(
        partialb + ((size_t)(z * kN + s * 12) * kN + a) * kC) + u;
    const float2* fb = reinterpret_cast<const float2*>(
        feat + (size_t)(z * kN + s * 12) * kC) + u;
#pragma unroll 4
    for (int q = 0; q < 12; ++q) {
        const unsigned int w = pb[(size_t)q * kN * (kC / 2)];
        a0 += bf2f((unsigned short)(w & 0xffffu));
        a1 += bf2f((unsigned short)(w >> 16));
        const float2 f2 = fb[q * (kC / 2)];
        s0 += f2.x; s1 += f2.y;
    }
    redV[s][2 * u]     = a0;
    redV[s][2 * u + 1] = a1;
    redS[s][2 * u]     = s0;
    redS[s][2 * u + 1] = s1;
    __syncthreads();

    if (tid < kC) {
        float v = 0.f, sv = 0.f;
#pragma unroll
        for (int q = 0; q < 16; ++q) { v += redV[q][tid]; sv += redS[q][tid]; }
        Vsh[tid] = v;
        Ssh[tid] = sv;
    }
    __syncthreads();

    if (tid < kC) {
        float bt = 0.f;
#pragma unroll
        for (int j = 0; j < kC; ++j) bt = fmaf(b2[tid * kC + j], Ssh[j], bt);
        dst[(size_t)blk * kC + tid] = (Vsh[tid] + bt) * kInvSqrtN * mask[z * kN + a];
    }
}

} // namespace

extern "C" void kernel_launch(void* const* d_in, const int* in_sizes, int n_in,
                              void* d_out, int out_size, void* d_ws, size_t ws_size,
                              hipStream_t stream) {
    const float* features = (const float*)d_in[0];
    const float* xyz      = (const float*)d_in[1];
    const float* mask     = (const float*)d_in[2];
    const float* W0       = (const float*)d_in[3];
    const float* b0       = (const float*)d_in[4];
    const float* W1       = (const float*)d_in[5];
    const float* b1       = (const float*)d_in[6];
    const float* W2       = (const float*)d_in[7];
    const float* b2       = (const float*)d_in[8];
    float* out = (float*)d_out;

    // workspace layout (float offsets):
    //   wb0     :       0 ..    2048   (4096 ushort  = 2 layers x 2048)
    //   wb1     :    2048 ..    6144   (8192 ushort  = 2 layers x 4096)
    //   Gb      :    6144 ..  399360   (786432 ushort = 1.5MB, reused per layer)
    //   partialb:  399360 .. 1579008   (2359296 ushort = 4.7MB)
    //   ftmp    : 1579008 .. 1591296
    float* ws = (float*)d_ws;
    unsigned short* wb0 = (unsigned short*)(ws);
    unsigned short* wb1 = (unsigned short*)(ws + 2048);
    unsigned short* Gb  = (unsigned short*)(ws + 6144);
    unsigned short* partialb = (unsigned short*)(ws + 399360);
    float* ftmp = ws + 1579008;

    // init: weight packing + layer-0 G
    init_kernel<<<34, 256, 0, stream>>>(W0, W1, features, W2, wb0, wb1, Gb);

    const float* cur = features;
    for (int l = 0; l < kLayers; ++l) {
        float* dst = (l == kLayers - 1) ? out : ftmp;
        if (l > 0)
            g_kernel<<<32, 256, 0, stream>>>(cur, W2 + (size_t)l * kH * kC * kC, Gb);
        fused_kernel<<<kB * kN, 256, 0, stream>>>(
            b0 + (size_t)l * kH, b1 + (size_t)l * kH,
            xyz, wb0 + (size_t)l * 2048, wb1 + (size_t)l * 4096,
            Gb, partialb);
        reduce_kernel<<<kB * kN, 256, 0, stream>>>(
            partialb, cur, b2 + (size_t)l * kC * kC, mask, dst);
        cur = dst;
    }
}